// Round 8
// baseline (383.439 us; speedup 1.0000x reference)
//
#include <hip/hip_runtime.h>
#include <math.h>

#define NN 512
#define CS 384
#define CZ 128
#define CH 16
#define HH 12
#define PQ 4
#define PV 8

typedef float f32x4 __attribute__((ext_vector_type(4)));
typedef __bf16 bf16x8 __attribute__((ext_vector_type(8)));

// ---------------- K0: repack weights into Wcat[384][1152] + bcat[1152] ----------------
__global__ void k_repack(const float* __restrict__ Wq,  const float* __restrict__ bq,
                         const float* __restrict__ Wkv, const float* __restrict__ bkv,
                         const float* __restrict__ Wqp, const float* __restrict__ bqp,
                         const float* __restrict__ Wkvp,const float* __restrict__ bkvp,
                         float* __restrict__ Wcat, float* __restrict__ bcat)
{
    const int total = CS * 1152;
    for (int idx = blockIdx.x * blockDim.x + threadIdx.x; idx < total; idx += gridDim.x * blockDim.x) {
        int kk = idx / 1152, n = idx % 1152;
        float vv;
        if (n < 192)      vv = Wq  [kk * 192 + n];
        else if (n < 576) vv = Wkv [kk * 384 + (n - 192)];
        else if (n < 720) vv = Wqp [kk * 144 + (n - 576)];
        else              vv = Wkvp[kk * 432 + (n - 720)];
        Wcat[idx] = vv;
    }
    int n = blockIdx.x * blockDim.x + threadIdx.x;
    if (n < 1152) {
        float vv;
        if (n < 192)      vv = bq  [n];
        else if (n < 576) vv = bkv [n - 192];
        else if (n < 720) vv = bqp [n - 576];
        else              vv = bkvp[n - 720];
        bcat[n] = vv;
    }
}

// ---------------- K1: s @ Wcat — BM=16 tiled GEMM; k written NATURAL [j][192] --------
__global__ void k_proj(const float* __restrict__ s, const float* __restrict__ Wcat,
                       const float* __restrict__ bcat,
                       float* __restrict__ q, float* __restrict__ k_n, float* __restrict__ v,
                       float* __restrict__ qp_raw, float* __restrict__ kvp_raw)
{
    __shared__ float As[16 * 68];
    __shared__ float Bs[64 * 64];

    int tx = threadIdx.x & 15;
    int ty = threadIdx.x >> 4;
    int n0 = blockIdx.x * 64;
    int m0 = blockIdx.y * 16;

    float acc[4] = {0.f, 0.f, 0.f, 0.f};

    for (int kb = 0; kb < CS; kb += 64) {
        #pragma unroll
        for (int e = 0; e < 4; ++e) {
            int idx = e * 256 + threadIdx.x;
            int m = idx >> 6, kk = idx & 63;
            As[m * 68 + kk] = s[(size_t)(m0 + m) * CS + kb + kk];
        }
        #pragma unroll
        for (int e = 0; e < 16; ++e) {
            int idx = e * 256 + threadIdx.x;
            int kk = idx >> 6, n = idx & 63;
            Bs[kk * 64 + n] = Wcat[(size_t)(kb + kk) * 1152 + n0 + n];
        }
        __syncthreads();

        for (int kk = 0; kk < 64; kk += 4) {
            f32x4 a = *(const f32x4*)&As[ty * 68 + kk];
            f32x4 b[4];
            #pragma unroll
            for (int kq = 0; kq < 4; ++kq)
                b[kq] = *(const f32x4*)&Bs[(kk + kq) * 64 + tx * 4];
            #pragma unroll
            for (int kq = 0; kq < 4; ++kq)
                #pragma unroll
                for (int cc = 0; cc < 4; ++cc)
                    acc[cc] += a[kq] * b[kq][cc];
        }
        __syncthreads();
    }

    int i = m0 + ty;
    #pragma unroll
    for (int cc = 0; cc < 4; ++cc) {
        int col = n0 + tx * 4 + cc;
        float val = acc[cc] + bcat[col];
        if (col < 192) {
            q[i * 192 + col] = val;
        } else if (col < 576) {
            int lc = col - 192;
            int h = lc / 32, w = lc % 32;
            if (w < CH) k_n[(size_t)i * 192 + h * CH + w] = val;        // natural
            else        v[(i * HH + h) * CH + (w - CH)] = val;
        } else if (col < 720) {
            qp_raw[i * 144 + (col - 576)] = val;
        } else {
            kvp_raw[i * 432 + (col - 720)] = val;
        }
    }
}

// ---------------- K2: rotate+translate; k_pts written NATURAL [j][144] ----------------
__global__ void k_pts_transform(const float* __restrict__ qp_raw, const float* __restrict__ kvp_raw,
                                const float* __restrict__ rot, const float* __restrict__ trans,
                                float* __restrict__ q_pts, float* __restrict__ k_pts_n,
                                float* __restrict__ v_pts)
{
    int idx = blockIdx.x * blockDim.x + threadIdx.x;
    const int total = NN * HH * 16;
    if (idx >= total) return;
    int i = idx / (HH * 16);
    int r = idx % (HH * 16);
    int h = r / 16;
    int p = r % 16;

    float R[9], t3[3];
    for (int a = 0; a < 9; ++a) R[a] = rot[i * 9 + a];
    for (int a = 0; a < 3; ++a) t3[a] = trans[i * 3 + a];

    float x, y, zc;
    if (p < PQ) {
        x  = qp_raw[i * 144 + 0 * 48 + h * PQ + p];
        y  = qp_raw[i * 144 + 1 * 48 + h * PQ + p];
        zc = qp_raw[i * 144 + 2 * 48 + h * PQ + p];
    } else {
        int pp = p - PQ;
        x  = kvp_raw[i * 432 + 0 * 144 + h * 12 + pp];
        y  = kvp_raw[i * 432 + 1 * 144 + h * 12 + pp];
        zc = kvp_raw[i * 432 + 2 * 144 + h * 12 + pp];
    }
    float ox = R[0] * x + R[1] * y + R[2] * zc + t3[0];
    float oy = R[3] * x + R[4] * y + R[5] * zc + t3[1];
    float oz = R[6] * x + R[7] * y + R[8] * zc + t3[2];

    if (p < PQ) {
        int o = ((i * HH + h) * PQ + p) * 3;
        q_pts[o] = ox; q_pts[o + 1] = oy; q_pts[o + 2] = oz;
    } else {
        int pp = p - PQ;
        if (pp < PQ) {
            int o = (size_t)i * 144 + (h * PQ + pp) * 3;   // natural
            k_pts_n[o] = ox; k_pts_n[o + 1] = oy; k_pts_n[o + 2] = oz;
        } else {
            int o = ((i * HH + h) * PV + (pp - PQ)) * 3;
            v_pts[o] = ox; v_pts[o + 1] = oy; v_pts[o + 2] = oz;
        }
    }
}

// ---------------- K_ATTN_PART: flash-style j-split, FLOAT4 loads everywhere ----------
// Block (i, jq) owns j in [jq*128, jq*128+128). All hot loads widened to float4:
// Phase B reads k/k_pts in natural per-row layout (4+3 float4/head); o/o_pt does one
// float4 v/v_pts load per j. Request-rate theory: ~250 scalar VMEM insts/thread was
// the invisible limiter (all pipes <25% at 81% occupancy).
__global__ void __launch_bounds__(512, 8)
k_attn_part(const float* __restrict__ z, const float* __restrict__ Wb,
            const float* __restrict__ bb,
            const float* __restrict__ q, const float* __restrict__ k_n,
            const float* __restrict__ q_pts, const float* __restrict__ k_pts_n,
            const float* __restrict__ head_weights, const float* __restrict__ mask,
            const float* __restrict__ v, const float* __restrict__ v_pts,
            float* __restrict__ stats, float* __restrict__ part,
            float* __restrict__ opair)
{
    __shared__ float lgs[HH][132];          // 6336 B
    __shared__ float q_lds[HH * CH];
    __shared__ float qp_lds[HH * PQ * 3];
    __shared__ float hw_lds[HH];
    __shared__ float bb_l[HH];
    __shared__ f32x4 pl[120][4];            // 7680 B (o/o_pt split-j partials)

    const int i  = blockIdx.x >> 2;
    const int jq = blockIdx.x & 3;
    const int j0 = jq * 128;
    const int tid = threadIdx.x;
    const int lane = tid & 63;
    const int wave = tid >> 6;
    const float* zbase = z + (size_t)i * NN * CZ;

    // ---- stage small per-i state ----
    if (tid < HH * CH)     q_lds[tid]  = q[(size_t)i * HH * CH + tid];
    if (tid < HH * PQ * 3) qp_lds[tid] = q_pts[(size_t)i * HH * PQ * 3 + tid];
    if (tid < HH) {
        float x = head_weights[tid];
        hw_lds[tid] = log1pf(expf(x)) * 0.13608276348795434f;  // softplus * sqrt(1/54)
        bb_l[tid] = bb[tid];
    }
    const float mask_i = mask[i];
    __syncthreads();

    // ---- Phase A: bias MFMA; wave w covers local j [16w, 16w+16); z float4 HBM ----
    {
        const float b_scale = 0.57735026918962576f;
        const int hcol = lane & 15;
        const int q8 = (lane >> 4) * 8;
        bf16x8 wbf[4];
        #pragma unroll
        for (int kc = 0; kc < 4; ++kc) {
            #pragma unroll
            for (int jj = 0; jj < 8; ++jj) {
                int c = kc * 32 + q8 + jj;
                float wv = (hcol < HH) ? Wb[c * HH + hcol] * b_scale : 0.0f;
                wbf[kc][jj] = (__bf16)wv;
            }
        }
        const int jl0 = wave * 16;
        const float* zrow = zbase + (size_t)(j0 + jl0 + hcol) * CZ;
        f32x4 acc = {0.f, 0.f, 0.f, 0.f};
        #pragma unroll
        for (int kc = 0; kc < 4; ++kc) {
            float4 z0 = *(const float4*)(zrow + kc * 32 + q8);
            float4 z1 = *(const float4*)(zrow + kc * 32 + q8 + 4);
            bf16x8 afrag;
            afrag[0] = (__bf16)z0.x; afrag[1] = (__bf16)z0.y;
            afrag[2] = (__bf16)z0.z; afrag[3] = (__bf16)z0.w;
            afrag[4] = (__bf16)z1.x; afrag[5] = (__bf16)z1.y;
            afrag[6] = (__bf16)z1.z; afrag[7] = (__bf16)z1.w;
            acc = __builtin_amdgcn_mfma_f32_16x16x32_bf16(afrag, wbf[kc], acc, 0, 0, 0);
        }
        if (hcol < HH) {
            #pragma unroll
            for (int r = 0; r < 4; ++r)
                lgs[hcol][jl0 + (lane >> 4) * 4 + r] = acc[r];
        }
    }
    __syncthreads();

    // ---- Phase B: logits; 4 h-groups x 128 cols; k/k_pts float4 natural rows ----
    {
        const float qk_scale = 0.14433756729740643f;  // sqrt(1/48)
        const float b_scale  = 0.57735026918962576f;  // sqrt(1/3)
        const int cl = tid & 127;
        const int j  = j0 + cl;
        const int hg = tid >> 7;           // 0..3 -> heads hg*3..hg*3+2 (wave-uniform)
        const float sqm = 100000.0f * (mask_i * mask[j] - 1.0f);
        const float* krow = k_n     + (size_t)j * 192 + hg * 48;
        const float* prow = k_pts_n + (size_t)j * 144 + hg * 36;
        #pragma unroll
        for (int hh = 0; hh < 3; ++hh) {
            int h = hg * 3 + hh;
            f32x4 k0 = *(const f32x4*)(krow + hh * 16 + 0);
            f32x4 k1 = *(const f32x4*)(krow + hh * 16 + 4);
            f32x4 k2 = *(const f32x4*)(krow + hh * 16 + 8);
            f32x4 k3 = *(const f32x4*)(krow + hh * 16 + 12);
            const float* ql = q_lds + h * CH;
            float accq = ql[0]*k0[0] + ql[1]*k0[1] + ql[2]*k0[2] + ql[3]*k0[3]
                       + ql[4]*k1[0] + ql[5]*k1[1] + ql[6]*k1[2] + ql[7]*k1[3]
                       + ql[8]*k2[0] + ql[9]*k2[1] + ql[10]*k2[2] + ql[11]*k2[3]
                       + ql[12]*k3[0] + ql[13]*k3[1] + ql[14]*k3[2] + ql[15]*k3[3];
            f32x4 pa = *(const f32x4*)(prow + hh * 12 + 0);
            f32x4 pb = *(const f32x4*)(prow + hh * 12 + 4);
            f32x4 pc = *(const f32x4*)(prow + hh * 12 + 8);
            const float* qh = qp_lds + h * 12;
            float t0 = qh[0]-pa[0],  t1 = qh[1]-pa[1],  t2 = qh[2]-pa[2],  t3 = qh[3]-pa[3];
            float t4 = qh[4]-pb[0],  t5 = qh[5]-pb[1],  t6 = qh[6]-pb[2],  t7 = qh[7]-pb[3];
            float t8 = qh[8]-pc[0],  t9 = qh[9]-pc[1],  t10= qh[10]-pc[2], t11= qh[11]-pc[3];
            float s2 = t0*t0 + t1*t1 + t2*t2 + t3*t3
                     + t4*t4 + t5*t5 + t6*t6 + t7*t7
                     + t8*t8 + t9*t9 + t10*t10 + t11*t11;
            lgs[h][cl] += accq * qk_scale + b_scale * bb_l[h] - 0.5f * hw_lds[h] * s2 + sqm;
        }
    }
    __syncthreads();

    // ---- partial softmax: wave w handles rows w, w+8; 2 vals/lane ----
    for (int row = wave; row < HH; row += 8) {
        float v0 = lgs[row][lane];
        float v1 = lgs[row][lane + 64];
        float m = fmaxf(v0, v1);
        #pragma unroll
        for (int off = 32; off >= 1; off >>= 1) m = fmaxf(m, __shfl_xor(m, off));
        float e0 = expf(v0 - m);
        float e1 = expf(v1 - m);
        float ss = e0 + e1;
        #pragma unroll
        for (int off = 32; off >= 1; off >>= 1) ss += __shfl_xor(ss, off);
        lgs[row][lane]      = e0;
        lgs[row][lane + 64] = e1;
        if (lane == 0) {
            size_t sb = ((size_t)(i * 4 + jq) * HH + row) * 2;
            stats[sb]     = m;
            stats[sb + 1] = ss;
        }
    }
    __syncthreads();

    // ---- o / o_pt partials: thread (f,jsub) = float4-output f over 32 j's ----
    if (tid < 480) {
        int f = tid >> 2, jsub = tid & 3;
        int h = (f < 48) ? (f >> 2) : ((f - 48) / 6);
        const float* lrj = lgs[h] + jsub * 32;
        const float* bp;
        int stride;
        if (f < 48) { bp = v     + (size_t)j0 * 192 + f * 4;        stride = 192; }
        else        { bp = v_pts + (size_t)j0 * 288 + (f - 48) * 4; stride = 288; }
        bp += (size_t)(jsub * 32) * stride;
        f32x4 acc = {0.f, 0.f, 0.f, 0.f};
        #pragma unroll 8
        for (int jj = 0; jj < 32; ++jj)
            acc += lrj[jj] * *(const f32x4*)(bp + (size_t)jj * stride);
        pl[f][jsub] = acc;
    }

    // ---- o_pair partial MFMA: p (LDS) x z (global, L2-hot own slice); 4 K-steps ----
    {
        int cl = lane & 15;
        int q4 = lane >> 4;
        int ha = (cl < HH) ? cl : (HH - 1);
        int cb = wave * 16 + cl;              // 0..127 = z channel
        f32x4 pacc = {0.f, 0.f, 0.f, 0.f};
        #pragma unroll
        for (int ks = 0; ks < 4; ++ks) {
            int jb = ks * 32 + q4 * 8;        // local j
            f32x4 a0 = *(const f32x4*)&lgs[ha][jb];
            f32x4 a1 = *(const f32x4*)&lgs[ha][jb + 4];
            bf16x8 af;
            af[0] = (__bf16)a0[0]; af[1] = (__bf16)a0[1];
            af[2] = (__bf16)a0[2]; af[3] = (__bf16)a0[3];
            af[4] = (__bf16)a1[0]; af[5] = (__bf16)a1[1];
            af[6] = (__bf16)a1[2]; af[7] = (__bf16)a1[3];
            bf16x8 bf;
            #pragma unroll
            for (int jj = 0; jj < 8; ++jj)
                bf[jj] = (__bf16)zbase[(size_t)(j0 + jb + jj) * CZ + cb];
            pacc = __builtin_amdgcn_mfma_f32_16x16x32_bf16(af, bf, pacc, 0, 0, 0);
        }
        #pragma unroll
        for (int r = 0; r < 4; ++r) {
            int h = q4 * 4 + r;
            if (h < HH)
                opair[(size_t)(i * 4 + jq) * 1536 + h * 128 + cb] = pacc[r];
        }
    }
    __syncthreads();

    // ---- combine split-j partials; float4 write ----
    if (tid < 120) {
        f32x4 s = pl[tid][0] + pl[tid][1] + pl[tid][2] + pl[tid][3];
        *(f32x4*)&part[(size_t)(i * 4 + jq) * 480 + tid * 4] = s;
    }
}

// ---------------- K_COMBINE: merge 4 j-quarters (flash combine) + frame + norms ------
__global__ void __launch_bounds__(512, 8)
k_combine(const float* __restrict__ stats, const float* __restrict__ part,
          const float* __restrict__ opair,
          const float* __restrict__ rot, const float* __restrict__ trans,
          float* __restrict__ cat)
{
    __shared__ float f_lds[HH][4];
    __shared__ float opt_lds[HH * PV * 3];

    const int i = blockIdx.x;
    const int tid = threadIdx.x;

    if (tid < HH) {
        float m[4], s[4];
        #pragma unroll
        for (int qq = 0; qq < 4; ++qq) {
            size_t sb = ((size_t)(i * 4 + qq) * HH + tid) * 2;
            m[qq] = stats[sb];
            s[qq] = stats[sb + 1];
        }
        float M = fmaxf(fmaxf(m[0], m[1]), fmaxf(m[2], m[3]));
        float Z = 0.f;
        float e[4];
        #pragma unroll
        for (int qq = 0; qq < 4; ++qq) { e[qq] = expf(m[qq] - M); Z += s[qq] * e[qq]; }
        float invZ = 1.0f / Z;
        #pragma unroll
        for (int qq = 0; qq < 4; ++qq) f_lds[tid][qq] = e[qq] * invZ;
    }
    __syncthreads();

    // ---- o and o_pt ----
    if (tid < 480) {
        int h = (tid < 192) ? (tid >> 4) : ((tid - 192) / 24);
        float acc = 0.f;
        #pragma unroll
        for (int qq = 0; qq < 4; ++qq)
            acc += f_lds[h][qq] * part[(size_t)(i * 4 + qq) * 480 + tid];
        if (tid < 192) cat[(size_t)i * 2112 + tid] = acc;
        else           opt_lds[tid - 192] = acc;
    }

    // ---- o_pair: 1536 outputs, 3 per thread ----
    #pragma unroll
    for (int k = 0; k < 3; ++k) {
        int idx = tid + k * 512;
        int h = idx >> 7;
        float acc = 0.f;
        #pragma unroll
        for (int qq = 0; qq < 4; ++qq)
            acc += f_lds[h][qq] * opair[(size_t)(i * 4 + qq) * 1536 + idx];
        cat[(size_t)i * 2112 + 576 + idx] = acc;
    }
    __syncthreads();

    // ---- inverse frame + norm ----
    if (tid < HH * PV) {
        int hp = tid;
        float R[9], t3[3];
        #pragma unroll
        for (int a2 = 0; a2 < 9; ++a2) R[a2] = rot[i * 9 + a2];
        #pragma unroll
        for (int a2 = 0; a2 < 3; ++a2) t3[a2] = trans[i * 3 + a2];
        float gx = opt_lds[hp * 3 + 0] - t3[0];
        float gy = opt_lds[hp * 3 + 1] - t3[1];
        float gz = opt_lds[hp * 3 + 2] - t3[2];
        float lx = R[0] * gx + R[3] * gy + R[6] * gz;
        float ly = R[1] * gx + R[4] * gy + R[7] * gz;
        float lz = R[2] * gx + R[5] * gy + R[8] * gz;
        float* crow = cat + (size_t)i * 2112;
        crow[192 + 0 * 96 + hp] = lx;
        crow[192 + 1 * 96 + hp] = ly;
        crow[192 + 2 * 96 + hp] = lz;
        crow[480 + hp] = sqrtf(lx * lx + ly * ly + lz * lz + 1e-8f);
    }
}

// ---------------- K7: out = cat @ Wout + bout — BM=16 split-K GEMM ----------------
__global__ void k_final(const float* __restrict__ cat, const float* __restrict__ Wout,
                        const float* __restrict__ bout, float* __restrict__ out)
{
    __shared__ float As[16 * 52];
    __shared__ float Bs[48 * 64];

    int tx = threadIdx.x & 15;
    int ty = threadIdx.x >> 4;
    int n0 = blockIdx.x * 64;
    int m0 = blockIdx.y * 16;
    int k0 = blockIdx.z * 528;

    float acc[4] = {0.f, 0.f, 0.f, 0.f};

    for (int stage = 0; stage < 11; ++stage) {
        int kb = k0 + stage * 48;
        #pragma unroll
        for (int e = 0; e < 3; ++e) {
            int idx = e * 256 + threadIdx.x;
            int m = idx / 48, kk = idx % 48;
            As[m * 52 + kk] = cat[(size_t)(m0 + m) * 2112 + kb + kk];
        }
        #pragma unroll
        for (int e = 0; e < 12; ++e) {
            int idx = e * 256 + threadIdx.x;
            int kk = idx >> 6, n = idx & 63;
            Bs[kk * 64 + n] = Wout[(size_t)(kb + kk) * 384 + n0 + n];
        }
        __syncthreads();

        for (int kk = 0; kk < 48; kk += 4) {
            f32x4 a = *(const f32x4*)&As[ty * 52 + kk];
            f32x4 b[4];
            #pragma unroll
            for (int kq = 0; kq < 4; ++kq)
                b[kq] = *(const f32x4*)&Bs[(kk + kq) * 64 + tx * 4];
            #pragma unroll
            for (int kq = 0; kq < 4; ++kq)
                #pragma unroll
                for (int cc = 0; cc < 4; ++cc)
                    acc[cc] += a[kq] * b[kq][cc];
        }
        __syncthreads();
    }

    bool add_bias = (blockIdx.z == 0);
    int m = m0 + ty;
    #pragma unroll
    for (int cc = 0; cc < 4; ++cc) {
        int n = n0 + tx * 4 + cc;
        float val = acc[cc] + (add_bias ? bout[n] : 0.f);
        atomicAdd(&out[(size_t)m * 384 + n], val);
    }
}

extern "C" void kernel_launch(void* const* d_in, const int* in_sizes, int n_in,
                              void* d_out, int out_size, void* d_ws, size_t ws_size,
                              hipStream_t stream)
{
    const float* s     = (const float*)d_in[0];
    const float* z     = (const float*)d_in[1];
    const float* rot   = (const float*)d_in[2];
    const float* trans = (const float*)d_in[3];
    const float* mask  = (const float*)d_in[4];
    const float* Wq    = (const float*)d_in[5];
    const float* bq    = (const float*)d_in[6];
    const float* Wkv   = (const float*)d_in[7];
    const float* bkv   = (const float*)d_in[8];
    const float* Wqp   = (const float*)d_in[9];
    const float* bqp   = (const float*)d_in[10];
    const float* Wkvp  = (const float*)d_in[11];
    const float* bkvp  = (const float*)d_in[12];
    const float* Wb    = (const float*)d_in[13];
    const float* bb    = (const float*)d_in[14];
    const float* hw    = (const float*)d_in[15];
    const float* Wout  = (const float*)d_in[16];
    const float* bout  = (const float*)d_in[17];
    float* out = (float*)d_out;

    float* ws = (float*)d_ws;
    float* q       = ws;             // 98304
    float* k_n     = ws + 98304;     // 98304 (natural [j][192])
    float* v       = ws + 196608;    // 98304
    float* qp_raw  = ws + 294912;    // 73728
    float* kvp_raw = ws + 368640;    // 221184
    float* q_pts   = ws + 589824;    // 73728
    float* k_pts_n = ws + 663552;    // 73728 (natural [j][144])
    float* v_pts   = ws + 737280;    // 147456
    float* cat     = ws + 884736;    // 1081344
    float* Wcat    = ws + 1966080;   // 442368
    float* bcat    = ws + 2408448;   // 1152
    float* stats   = ws + 2409600;   // 49152
    float* part    = ws + 2458752;   // 983040
    float* opairb  = ws + 3441792;   // 3145728

    hipMemsetAsync(out, 0, (size_t)NN * CS * sizeof(float), stream);

    hipLaunchKernelGGL(k_repack, dim3(512), dim3(256), 0, stream,
                       Wq, bq, Wkv, bkv, Wqp, bqp, Wkvp, bkvp, Wcat, bcat);
    hipLaunchKernelGGL(k_proj, dim3(18, 32), dim3(256), 0, stream,
                       s, Wcat, bcat, q, k_n, v, qp_raw, kvp_raw);
    hipLaunchKernelGGL(k_pts_transform, dim3(384), dim3(256), 0, stream,
                       qp_raw, kvp_raw, rot, trans, q_pts, k_pts_n, v_pts);
    hipLaunchKernelGGL(k_attn_part, dim3(NN * 4), dim3(512), 0, stream,
                       z, Wb, bb, q, k_n, q_pts, k_pts_n, hw, mask,
                       v, v_pts, stats, part, opairb);
    hipLaunchKernelGGL(k_combine, dim3(NN), dim3(512), 0, stream,
                       stats, part, opairb, rot, trans, cat);
    hipLaunchKernelGGL(k_final, dim3(6, 32, 4), dim3(256), 0, stream, cat, Wout, bout, out);
}

// Round 11
// 333.096 us; speedup vs baseline: 1.1511x; 1.1511x over previous
//
#include <hip/hip_runtime.h>
#include <math.h>

#define NN 512
#define CS 384
#define CZ 128
#define CH 16
#define HH 12
#define PQ 4
#define PV 8

typedef float f32x4 __attribute__((ext_vector_type(4)));
typedef __bf16 bf16x8 __attribute__((ext_vector_type(8)));

// ---------------- K0: repack weights into Wcat[384][1152] + bcat[1152] ----------------
__global__ void k_repack(const float* __restrict__ Wq,  const float* __restrict__ bq,
                         const float* __restrict__ Wkv, const float* __restrict__ bkv,
                         const float* __restrict__ Wqp, const float* __restrict__ bqp,
                         const float* __restrict__ Wkvp,const float* __restrict__ bkvp,
                         float* __restrict__ Wcat, float* __restrict__ bcat)
{
    const int total = CS * 1152;
    for (int idx = blockIdx.x * blockDim.x + threadIdx.x; idx < total; idx += gridDim.x * blockDim.x) {
        int kk = idx / 1152, n = idx % 1152;
        float vv;
        if (n < 192)      vv = Wq  [kk * 192 + n];
        else if (n < 576) vv = Wkv [kk * 384 + (n - 192)];
        else if (n < 720) vv = Wqp [kk * 144 + (n - 576)];
        else              vv = Wkvp[kk * 432 + (n - 720)];
        Wcat[idx] = vv;
    }
    int n = blockIdx.x * blockDim.x + threadIdx.x;
    if (n < 1152) {
        float vv;
        if (n < 192)      vv = bq  [n];
        else if (n < 576) vv = bkv [n - 192];
        else if (n < 720) vv = bqp [n - 576];
        else              vv = bkvp[n - 720];
        bcat[n] = vv;
    }
}

// ---------------- K1: s @ Wcat — BM=16 GEMM; k stored INTERLEAVED-PACKED --------------
// kpack layout (f32x4 units): kpack4[(h*4+g)*NN + j] = k[j][h*16+4g .. +3]
__global__ void k_proj(const float* __restrict__ s, const float* __restrict__ Wcat,
                       const float* __restrict__ bcat,
                       float* __restrict__ q, float* __restrict__ kpack, float* __restrict__ v,
                       float* __restrict__ qp_raw, float* __restrict__ kvp_raw)
{
    __shared__ float As[16 * 68];
    __shared__ float Bs[64 * 64];

    int tx = threadIdx.x & 15;
    int ty = threadIdx.x >> 4;
    int n0 = blockIdx.x * 64;
    int m0 = blockIdx.y * 16;

    float acc[4] = {0.f, 0.f, 0.f, 0.f};

    for (int kb = 0; kb < CS; kb += 64) {
        #pragma unroll
        for (int e = 0; e < 4; ++e) {
            int idx = e * 256 + threadIdx.x;
            int m = idx >> 6, kk = idx & 63;
            As[m * 68 + kk] = s[(size_t)(m0 + m) * CS + kb + kk];
        }
        #pragma unroll
        for (int e = 0; e < 16; ++e) {
            int idx = e * 256 + threadIdx.x;
            int kk = idx >> 6, n = idx & 63;
            Bs[kk * 64 + n] = Wcat[(size_t)(kb + kk) * 1152 + n0 + n];
        }
        __syncthreads();

        for (int kk = 0; kk < 64; kk += 4) {
            f32x4 a = *(const f32x4*)&As[ty * 68 + kk];
            f32x4 b[4];
            #pragma unroll
            for (int kq = 0; kq < 4; ++kq)
                b[kq] = *(const f32x4*)&Bs[(kk + kq) * 64 + tx * 4];
            #pragma unroll
            for (int kq = 0; kq < 4; ++kq)
                #pragma unroll
                for (int cc = 0; cc < 4; ++cc)
                    acc[cc] += a[kq] * b[kq][cc];
        }
        __syncthreads();
    }

    int i = m0 + ty;
    #pragma unroll
    for (int cc = 0; cc < 4; ++cc) {
        int col = n0 + tx * 4 + cc;
        float val = acc[cc] + bcat[col];
        if (col < 192) {
            q[i * 192 + col] = val;
        } else if (col < 576) {
            int lc = col - 192;
            int h = lc / 32, w = lc % 32;
            if (w < CH) kpack[(size_t)(((h * 4 + (w >> 2)) * NN + i) * 4 + (w & 3))] = val;
            else        v[(size_t)i * 192 + h * CH + (w - CH)] = val;
        } else if (col < 720) {
            qp_raw[i * 144 + (col - 576)] = val;
        } else {
            kvp_raw[i * 432 + (col - 720)] = val;
        }
    }
}

// ---------------- K2: rotate+translate; k_pts stored INTERLEAVED-PACKED ---------------
// kppack layout (f32x4 units): kppack4[(h*3+g)*NN + j] = kp[j][h*12+4g .. +3]
__global__ void k_pts_transform(const float* __restrict__ qp_raw, const float* __restrict__ kvp_raw,
                                const float* __restrict__ rot, const float* __restrict__ trans,
                                float* __restrict__ q_pts, float* __restrict__ kppack,
                                float* __restrict__ v_pts)
{
    int idx = blockIdx.x * blockDim.x + threadIdx.x;
    const int total = NN * HH * 16;
    if (idx >= total) return;
    int i = idx / (HH * 16);
    int r = idx % (HH * 16);
    int h = r / 16;
    int p = r % 16;

    float R[9], t3[3];
    for (int a = 0; a < 9; ++a) R[a] = rot[i * 9 + a];
    for (int a = 0; a < 3; ++a) t3[a] = trans[i * 3 + a];

    float x, y, zc;
    if (p < PQ) {
        x  = qp_raw[i * 144 + 0 * 48 + h * PQ + p];
        y  = qp_raw[i * 144 + 1 * 48 + h * PQ + p];
        zc = qp_raw[i * 144 + 2 * 48 + h * PQ + p];
    } else {
        int pp = p - PQ;
        x  = kvp_raw[i * 432 + 0 * 144 + h * 12 + pp];
        y  = kvp_raw[i * 432 + 1 * 144 + h * 12 + pp];
        zc = kvp_raw[i * 432 + 2 * 144 + h * 12 + pp];
    }
    float ox = R[0] * x + R[1] * y + R[2] * zc + t3[0];
    float oy = R[3] * x + R[4] * y + R[5] * zc + t3[1];
    float oz = R[6] * x + R[7] * y + R[8] * zc + t3[2];

    if (p < PQ) {
        int o = ((i * HH + h) * PQ + p) * 3;
        q_pts[o] = ox; q_pts[o + 1] = oy; q_pts[o + 2] = oz;
    } else {
        int pp = p - PQ;
        if (pp < PQ) {
            int d0 = pp * 3;
            kppack[(size_t)(((h * 3 + ((d0+0) >> 2)) * NN + i) * 4 + ((d0+0) & 3))] = ox;
            kppack[(size_t)(((h * 3 + ((d0+1) >> 2)) * NN + i) * 4 + ((d0+1) & 3))] = oy;
            kppack[(size_t)(((h * 3 + ((d0+2) >> 2)) * NN + i) * 4 + ((d0+2) & 3))] = oz;
        } else {
            int o = ((i * HH + h) * PV + (pp - PQ)) * 3;
            v_pts[o] = ox; v_pts[o + 1] = oy; v_pts[o + 2] = oz;
        }
    }
}

// ---------------- K_ATTN_PART: j-split, float4 loads with CORRECT coalescing ----------
// All hot loads are 16B/lane with lane-consecutive addresses (16 fully-utilized
// lines/wave): kpack/kppack interleaved [h][g][j][4]; v/v_pts consumed as float4 of
// OUTPUTS (lane = f4, natural [j][outs] layout is already packed that way).
// Wave-VMEM insts/block: ~1984 (r7) -> ~776, same bytes, same lines.
__global__ void __launch_bounds__(512, 8)
k_attn_part(const float* __restrict__ z, const float* __restrict__ Wb,
            const float* __restrict__ bb,
            const float* __restrict__ q, const float* __restrict__ kpack,
            const float* __restrict__ q_pts, const float* __restrict__ kppack,
            const float* __restrict__ head_weights, const float* __restrict__ mask,
            const float* __restrict__ v, const float* __restrict__ v_pts,
            float* __restrict__ stats, float* __restrict__ part,
            float* __restrict__ opair)
{
    __shared__ float lgs[HH][132];          // 6336 B
    __shared__ float q_lds[HH * CH];
    __shared__ float qp_lds[HH * PQ * 3];
    __shared__ float hw_lds[HH];
    __shared__ float bb_l[HH];
    __shared__ f32x4 pl[120][4];            // 7680 B (o/o_pt split-j partials)

    const int i  = blockIdx.x >> 2;
    const int jq = blockIdx.x & 3;
    const int j0 = jq * 128;
    const int tid = threadIdx.x;
    const int lane = tid & 63;
    const int wave = tid >> 6;
    const float* zbase = z + (size_t)i * NN * CZ;

    // ---- stage small per-i state ----
    if (tid < HH * CH)     q_lds[tid]  = q[(size_t)i * HH * CH + tid];
    if (tid < HH * PQ * 3) qp_lds[tid] = q_pts[(size_t)i * HH * PQ * 3 + tid];
    if (tid < HH) {
        float x = head_weights[tid];
        hw_lds[tid] = log1pf(expf(x)) * 0.13608276348795434f;  // softplus * sqrt(1/54)
        bb_l[tid] = bb[tid];
    }
    const float mask_i = mask[i];
    __syncthreads();

    // ---- Phase A: bias MFMA; wave w covers local j [16w, 16w+16); z float4 HBM ----
    {
        const float b_scale = 0.57735026918962576f;
        const int hcol = lane & 15;
        const int q8 = (lane >> 4) * 8;
        bf16x8 wbf[4];
        #pragma unroll
        for (int kc = 0; kc < 4; ++kc) {
            #pragma unroll
            for (int jj = 0; jj < 8; ++jj) {
                int c = kc * 32 + q8 + jj;
                float wv = (hcol < HH) ? Wb[c * HH + hcol] * b_scale : 0.0f;
                wbf[kc][jj] = (__bf16)wv;
            }
        }
        const int jl0 = wave * 16;
        const float* zrow = zbase + (size_t)(j0 + jl0 + hcol) * CZ;
        f32x4 acc = {0.f, 0.f, 0.f, 0.f};
        #pragma unroll
        for (int kc = 0; kc < 4; ++kc) {
            float4 z0 = *(const float4*)(zrow + kc * 32 + q8);
            float4 z1 = *(const float4*)(zrow + kc * 32 + q8 + 4);
            bf16x8 afrag;
            afrag[0] = (__bf16)z0.x; afrag[1] = (__bf16)z0.y;
            afrag[2] = (__bf16)z0.z; afrag[3] = (__bf16)z0.w;
            afrag[4] = (__bf16)z1.x; afrag[5] = (__bf16)z1.y;
            afrag[6] = (__bf16)z1.z; afrag[7] = (__bf16)z1.w;
            acc = __builtin_amdgcn_mfma_f32_16x16x32_bf16(afrag, wbf[kc], acc, 0, 0, 0);
        }
        if (hcol < HH) {
            #pragma unroll
            for (int r = 0; r < 4; ++r)
                lgs[hcol][jl0 + (lane >> 4) * 4 + r] = acc[r];
        }
    }
    __syncthreads();

    // ---- Phase B: logits; 4 h-groups x 128 cols; packed float4, lane-coalesced ----
    {
        const float qk_scale = 0.14433756729740643f;  // sqrt(1/48)
        const float b_scale  = 0.57735026918962576f;  // sqrt(1/3)
        const int cl = tid & 127;
        const int j  = j0 + cl;
        const int hg = tid >> 7;           // 0..3 -> heads hg*3..hg*3+2 (wave-uniform)
        const float sqm = 100000.0f * (mask_i * mask[j] - 1.0f);
        const f32x4* kp4  = (const f32x4*)kpack;
        const f32x4* kpp4 = (const f32x4*)kppack;
        #pragma unroll
        for (int hh = 0; hh < 3; ++hh) {
            int h = hg * 3 + hh;
            const f32x4* kb = kp4 + (size_t)(h * 4) * NN + j;
            f32x4 k0 = kb[0 * NN];
            f32x4 k1 = kb[1 * NN];
            f32x4 k2 = kb[2 * NN];
            f32x4 k3 = kb[3 * NN];
            const float* ql = q_lds + h * CH;
            float accq = ql[0]*k0[0] + ql[1]*k0[1] + ql[2]*k0[2] + ql[3]*k0[3]
                       + ql[4]*k1[0] + ql[5]*k1[1] + ql[6]*k1[2] + ql[7]*k1[3]
                       + ql[8]*k2[0] + ql[9]*k2[1] + ql[10]*k2[2] + ql[11]*k2[3]
                       + ql[12]*k3[0] + ql[13]*k3[1] + ql[14]*k3[2] + ql[15]*k3[3];
            const f32x4* pb = kpp4 + (size_t)(h * 3) * NN + j;
            f32x4 pa = pb[0 * NN];
            f32x4 pm = pb[1 * NN];
            f32x4 pc = pb[2 * NN];
            const float* qh = qp_lds + h * 12;
            float t0 = qh[0]-pa[0],  t1 = qh[1]-pa[1],  t2 = qh[2]-pa[2],  t3 = qh[3]-pa[3];
            float t4 = qh[4]-pm[0],  t5 = qh[5]-pm[1],  t6 = qh[6]-pm[2],  t7 = qh[7]-pm[3];
            float t8 = qh[8]-pc[0],  t9 = qh[9]-pc[1],  t10= qh[10]-pc[2], t11= qh[11]-pc[3];
            float s2 = t0*t0 + t1*t1 + t2*t2 + t3*t3
                     + t4*t4 + t5*t5 + t6*t6 + t7*t7
                     + t8*t8 + t9*t9 + t10*t10 + t11*t11;
            lgs[h][cl] += accq * qk_scale + b_scale * bb_l[h] - 0.5f * hw_lds[h] * s2 + sqm;
        }
    }
    __syncthreads();

    // ---- partial softmax: wave w handles rows w, w+8; 2 vals/lane ----
    for (int row = wave; row < HH; row += 8) {
        float v0 = lgs[row][lane];
        float v1 = lgs[row][lane + 64];
        float m = fmaxf(v0, v1);
        #pragma unroll
        for (int off = 32; off >= 1; off >>= 1) m = fmaxf(m, __shfl_xor(m, off));
        float e0 = expf(v0 - m);
        float e1 = expf(v1 - m);
        float ss = e0 + e1;
        #pragma unroll
        for (int off = 32; off >= 1; off >>= 1) ss += __shfl_xor(ss, off);
        lgs[row][lane]      = e0;
        lgs[row][lane + 64] = e1;
        if (lane == 0) {
            size_t sb = ((size_t)(i * 4 + jq) * HH + row) * 2;
            stats[sb]     = m;
            stats[sb + 1] = ss;
        }
    }
    __syncthreads();

    // ---- o / o_pt partials: thread = (jsub, f4); lane-consecutive f4 -> coalesced ----
    if (tid < 480) {
        int jsub = tid / 120;         // 0..3 (slow index: lanes share jsub)
        int f4   = tid % 120;         // 0..119 float4-output (fast across lanes)
        int h = (f4 < 48) ? (f4 >> 2) : ((f4 - 48) / 6);
        const float* lrj = lgs[h] + jsub * 32;
        const float* bp;
        int stride;
        if (f4 < 48) { bp = v     + (size_t)j0 * 192 + f4 * 4;        stride = 192; }
        else         { bp = v_pts + (size_t)j0 * 288 + (f4 - 48) * 4; stride = 288; }
        bp += (size_t)(jsub * 32) * stride;
        f32x4 acc = {0.f, 0.f, 0.f, 0.f};
        #pragma unroll 8
        for (int jj = 0; jj < 32; ++jj)
            acc += lrj[jj] * *(const f32x4*)(bp + (size_t)jj * stride);
        pl[f4][jsub] = acc;
    }

    // ---- o_pair partial MFMA: p (LDS) x z (global, L2-hot own slice); 4 K-steps ----
    {
        int cl = lane & 15;
        int q4 = lane >> 4;
        int ha = (cl < HH) ? cl : (HH - 1);
        int cb = wave * 16 + cl;              // 0..127 = z channel
        f32x4 pacc = {0.f, 0.f, 0.f, 0.f};
        #pragma unroll
        for (int ks = 0; ks < 4; ++ks) {
            int jb = ks * 32 + q4 * 8;        // local j
            f32x4 a0 = *(const f32x4*)&lgs[ha][jb];
            f32x4 a1 = *(const f32x4*)&lgs[ha][jb + 4];
            bf16x8 af;
            af[0] = (__bf16)a0[0]; af[1] = (__bf16)a0[1];
            af[2] = (__bf16)a0[2]; af[3] = (__bf16)a0[3];
            af[4] = (__bf16)a1[0]; af[5] = (__bf16)a1[1];
            af[6] = (__bf16)a1[2]; af[7] = (__bf16)a1[3];
            bf16x8 bf;
            #pragma unroll
            for (int jj = 0; jj < 8; ++jj)
                bf[jj] = (__bf16)zbase[(size_t)(j0 + jb + jj) * CZ + cb];
            pacc = __builtin_amdgcn_mfma_f32_16x16x32_bf16(af, bf, pacc, 0, 0, 0);
        }
        #pragma unroll
        for (int r = 0; r < 4; ++r) {
            int h = q4 * 4 + r;
            if (h < HH)
                opair[(size_t)(i * 4 + jq) * 1536 + h * 128 + cb] = pacc[r];
        }
    }
    __syncthreads();

    // ---- combine split-j partials; float4 write ----
    if (tid < 120) {
        f32x4 s = pl[tid][0] + pl[tid][1] + pl[tid][2] + pl[tid][3];
        *(f32x4*)&part[(size_t)(i * 4 + jq) * 480 + tid * 4] = s;
    }
}

// ---------------- K_COMBINE: merge 4 j-quarters (flash combine) + frame + norms ------
__global__ void __launch_bounds__(512, 8)
k_combine(const float* __restrict__ stats, const float* __restrict__ part,
          const float* __restrict__ opair,
          const float* __restrict__ rot, const float* __restrict__ trans,
          float* __restrict__ cat)
{
    __shared__ float f_lds[HH][4];
    __shared__ float opt_lds[HH * PV * 3];

    const int i = blockIdx.x;
    const int tid = threadIdx.x;

    if (tid < HH) {
        float m[4], s[4];
        #pragma unroll
        for (int qq = 0; qq < 4; ++qq) {
            size_t sb = ((size_t)(i * 4 + qq) * HH + tid) * 2;
            m[qq] = stats[sb];
            s[qq] = stats[sb + 1];
        }
        float M = fmaxf(fmaxf(m[0], m[1]), fmaxf(m[2], m[3]));
        float Z = 0.f;
        float e[4];
        #pragma unroll
        for (int qq = 0; qq < 4; ++qq) { e[qq] = expf(m[qq] - M); Z += s[qq] * e[qq]; }
        float invZ = 1.0f / Z;
        #pragma unroll
        for (int qq = 0; qq < 4; ++qq) f_lds[tid][qq] = e[qq] * invZ;
    }
    __syncthreads();

    // ---- o and o_pt ----
    if (tid < 480) {
        int h = (tid < 192) ? (tid >> 4) : ((tid - 192) / 24);
        float acc = 0.f;
        #pragma unroll
        for (int qq = 0; qq < 4; ++qq)
            acc += f_lds[h][qq] * part[(size_t)(i * 4 + qq) * 480 + tid];
        if (tid < 192) cat[(size_t)i * 2112 + tid] = acc;
        else           opt_lds[tid - 192] = acc;
    }

    // ---- o_pair: 1536 outputs, 3 per thread ----
    #pragma unroll
    for (int k = 0; k < 3; ++k) {
        int idx = tid + k * 512;
        int h = idx >> 7;
        float acc = 0.f;
        #pragma unroll
        for (int qq = 0; qq < 4; ++qq)
            acc += f_lds[h][qq] * opair[(size_t)(i * 4 + qq) * 1536 + idx];
        cat[(size_t)i * 2112 + 576 + idx] = acc;
    }
    __syncthreads();

    // ---- inverse frame + norm ----
    if (tid < HH * PV) {
        int hp = tid;
        float R[9], t3[3];
        #pragma unroll
        for (int a2 = 0; a2 < 9; ++a2) R[a2] = rot[i * 9 + a2];
        #pragma unroll
        for (int a2 = 0; a2 < 3; ++a2) t3[a2] = trans[i * 3 + a2];
        float gx = opt_lds[hp * 3 + 0] - t3[0];
        float gy = opt_lds[hp * 3 + 1] - t3[1];
        float gz = opt_lds[hp * 3 + 2] - t3[2];
        float lx = R[0] * gx + R[3] * gy + R[6] * gz;
        float ly = R[1] * gx + R[4] * gy + R[7] * gz;
        float lz = R[2] * gx + R[5] * gy + R[8] * gz;
        float* crow = cat + (size_t)i * 2112;
        crow[192 + 0 * 96 + hp] = lx;
        crow[192 + 1 * 96 + hp] = ly;
        crow[192 + 2 * 96 + hp] = lz;
        crow[480 + hp] = sqrtf(lx * lx + ly * ly + lz * lz + 1e-8f);
    }
}

// ---------------- K7: out = cat @ Wout + bout — BM=16 split-K GEMM ----------------
__global__ void k_final(const float* __restrict__ cat, const float* __restrict__ Wout,
                        const float* __restrict__ bout, float* __restrict__ out)
{
    __shared__ float As[16 * 52];
    __shared__ float Bs[48 * 64];

    int tx = threadIdx.x & 15;
    int ty = threadIdx.x >> 4;
    int n0 = blockIdx.x * 64;
    int m0 = blockIdx.y * 16;
    int k0 = blockIdx.z * 528;

    float acc[4] = {0.f, 0.f, 0.f, 0.f};

    for (int stage = 0; stage < 11; ++stage) {
        int kb = k0 + stage * 48;
        #pragma unroll
        for (int e = 0; e < 3; ++e) {
            int idx = e * 256 + threadIdx.x;
            int m = idx / 48, kk = idx % 48;
            As[m * 52 + kk] = cat[(size_t)(m0 + m) * 2112 + kb + kk];
        }
        #pragma unroll
        for (int e = 0; e < 12; ++e) {
            int idx = e * 256 + threadIdx.x;
            int kk = idx >> 6, n = idx & 63;
            Bs[kk * 64 + n] = Wout[(size_t)(kb + kk) * 384 + n0 + n];
        }
        __syncthreads();

        for (int kk = 0; kk < 48; kk += 4) {
            f32x4 a = *(const f32x4*)&As[ty * 52 + kk];
            f32x4 b[4];
            #pragma unroll
            for (int kq = 0; kq < 4; ++kq)
                b[kq] = *(const f32x4*)&Bs[(kk + kq) * 64 + tx * 4];
            #pragma unroll
            for (int kq = 0; kq < 4; ++kq)
                #pragma unroll
                for (int cc = 0; cc < 4; ++cc)
                    acc[cc] += a[kq] * b[kq][cc];
        }
        __syncthreads();
    }

    bool add_bias = (blockIdx.z == 0);
    int m = m0 + ty;
    #pragma unroll
    for (int cc = 0; cc < 4; ++cc) {
        int n = n0 + tx * 4 + cc;
        float val = acc[cc] + (add_bias ? bout[n] : 0.f);
        atomicAdd(&out[(size_t)m * 384 + n], val);
    }
}

extern "C" void kernel_launch(void* const* d_in, const int* in_sizes, int n_in,
                              void* d_out, int out_size, void* d_ws, size_t ws_size,
                              hipStream_t stream)
{
    const float* s     = (const float*)d_in[0];
    const float* z     = (const float*)d_in[1];
    const float* rot   = (const float*)d_in[2];
    const float* trans = (const float*)d_in[3];
    const float* mask  = (const float*)d_in[4];
    const float* Wq    = (const float*)d_in[5];
    const float* bq    = (const float*)d_in[6];
    const float* Wkv   = (const float*)d_in[7];
    const float* bkv   = (const float*)d_in[8];
    const float* Wqp   = (const float*)d_in[9];
    const float* bqp   = (const float*)d_in[10];
    const float* Wkvp  = (const float*)d_in[11];
    const float* bkvp  = (const float*)d_in[12];
    const float* Wb    = (const float*)d_in[13];
    const float* bb    = (const float*)d_in[14];
    const float* hw    = (const float*)d_in[15];
    const float* Wout  = (const float*)d_in[16];
    const float* bout  = (const float*)d_in[17];
    float* out = (float*)d_out;

    float* ws = (float*)d_ws;
    float* q       = ws;             // 98304
    float* kpack   = ws + 98304;     // 98304 (interleaved [h][4][j][4])
    float* v       = ws + 196608;    // 98304 (natural [j][192])
    float* qp_raw  = ws + 294912;    // 73728
    float* kvp_raw = ws + 368640;    // 221184
    float* q_pts   = ws + 589824;    // 73728
    float* kppack  = ws + 663552;    // 73728 (interleaved [h][3][j][4])
    float* v_pts   = ws + 737280;    // 147456 (natural [j][288])
    float* cat     = ws + 884736;    // 1081344
    float* Wcat    = ws + 1966080;   // 442368
    float* bcat    = ws + 2408448;   // 1152
    float* stats   = ws + 2409600;   // 49152
    float* part    = ws + 2458752;   // 983040
    float* opairb  = ws + 3441792;   // 3145728

    hipMemsetAsync(out, 0, (size_t)NN * CS * sizeof(float), stream);

    hipLaunchKernelGGL(k_repack, dim3(512), dim3(256), 0, stream,
                       Wq, bq, Wkv, bkv, Wqp, bqp, Wkvp, bkvp, Wcat, bcat);
    hipLaunchKernelGGL(k_proj, dim3(18, 32), dim3(256), 0, stream,
                       s, Wcat, bcat, q, kpack, v, qp_raw, kvp_raw);
    hipLaunchKernelGGL(k_pts_transform, dim3(384), dim3(256), 0, stream,
                       qp_raw, kvp_raw, rot, trans, q_pts, kppack, v_pts);
    hipLaunchKernelGGL(k_attn_part, dim3(NN * 4), dim3(512), 0, stream,
                       z, Wb, bb, q, kpack, q_pts, kppack, hw, mask,
                       v, v_pts, stats, part, opairb);
    hipLaunchKernelGGL(k_combine, dim3(NN), dim3(512), 0, stream,
                       stats, part, opairb, rot, trans, cat);
    hipLaunchKernelGGL(k_final, dim3(6, 32, 4), dim3(256), 0, stream, cat, Wout, bout, out);
}

// Round 12
// 332.837 us; speedup vs baseline: 1.1520x; 1.0008x over previous
//
#include <hip/hip_runtime.h>
#include <math.h>

#define NN 512
#define CS 384
#define CZ 128
#define CH 16
#define HH 12
#define PQ 4
#define PV 8

typedef float f32x4 __attribute__((ext_vector_type(4)));
typedef __bf16 bf16x8 __attribute__((ext_vector_type(8)));

// ---------------- K0: repack weights into Wcat[384][1152] + bcat[1152] ----------------
__global__ void k_repack(const float* __restrict__ Wq,  const float* __restrict__ bq,
                         const float* __restrict__ Wkv, const float* __restrict__ bkv,
                         const float* __restrict__ Wqp, const float* __restrict__ bqp,
                         const float* __restrict__ Wkvp,const float* __restrict__ bkvp,
                         float* __restrict__ Wcat, float* __restrict__ bcat)
{
    const int total = CS * 1152;
    for (int idx = blockIdx.x * blockDim.x + threadIdx.x; idx < total; idx += gridDim.x * blockDim.x) {
        int kk = idx / 1152, n = idx % 1152;
        float vv;
        if (n < 192)      vv = Wq  [kk * 192 + n];
        else if (n < 576) vv = Wkv [kk * 384 + (n - 192)];
        else if (n < 720) vv = Wqp [kk * 144 + (n - 576)];
        else              vv = Wkvp[kk * 432 + (n - 720)];
        Wcat[idx] = vv;
    }
    int n = blockIdx.x * blockDim.x + threadIdx.x;
    if (n < 1152) {
        float vv;
        if (n < 192)      vv = bq  [n];
        else if (n < 576) vv = bkv [n - 192];
        else if (n < 720) vv = bqp [n - 576];
        else              vv = bkvp[n - 720];
        bcat[n] = vv;
    }
}

// ---------------- K1: s @ Wcat — BM=16 GEMM; k stored INTERLEAVED-PACKED --------------
// kpack layout (f32x4 units): kpack4[(h*4+g)*NN + j] = k[j][h*16+4g .. +3]
__global__ void k_proj(const float* __restrict__ s, const float* __restrict__ Wcat,
                       const float* __restrict__ bcat,
                       float* __restrict__ q, float* __restrict__ kpack, float* __restrict__ v,
                       float* __restrict__ qp_raw, float* __restrict__ kvp_raw)
{
    __shared__ float As[16 * 68];
    __shared__ float Bs[64 * 64];

    int tx = threadIdx.x & 15;
    int ty = threadIdx.x >> 4;
    int n0 = blockIdx.x * 64;
    int m0 = blockIdx.y * 16;

    float acc[4] = {0.f, 0.f, 0.f, 0.f};

    for (int kb = 0; kb < CS; kb += 64) {
        #pragma unroll
        for (int e = 0; e < 4; ++e) {
            int idx = e * 256 + threadIdx.x;
            int m = idx >> 6, kk = idx & 63;
            As[m * 68 + kk] = s[(size_t)(m0 + m) * CS + kb + kk];
        }
        #pragma unroll
        for (int e = 0; e < 16; ++e) {
            int idx = e * 256 + threadIdx.x;
            int kk = idx >> 6, n = idx & 63;
            Bs[kk * 64 + n] = Wcat[(size_t)(kb + kk) * 1152 + n0 + n];
        }
        __syncthreads();

        for (int kk = 0; kk < 64; kk += 4) {
            f32x4 a = *(const f32x4*)&As[ty * 68 + kk];
            f32x4 b[4];
            #pragma unroll
            for (int kq = 0; kq < 4; ++kq)
                b[kq] = *(const f32x4*)&Bs[(kk + kq) * 64 + tx * 4];
            #pragma unroll
            for (int kq = 0; kq < 4; ++kq)
                #pragma unroll
                for (int cc = 0; cc < 4; ++cc)
                    acc[cc] += a[kq] * b[kq][cc];
        }
        __syncthreads();
    }

    int i = m0 + ty;
    #pragma unroll
    for (int cc = 0; cc < 4; ++cc) {
        int col = n0 + tx * 4 + cc;
        float val = acc[cc] + bcat[col];
        if (col < 192) {
            q[i * 192 + col] = val;
        } else if (col < 576) {
            int lc = col - 192;
            int h = lc / 32, w = lc % 32;
            if (w < CH) kpack[(size_t)(((h * 4 + (w >> 2)) * NN + i) * 4 + (w & 3))] = val;
            else        v[(size_t)i * 192 + h * CH + (w - CH)] = val;
        } else if (col < 720) {
            qp_raw[i * 144 + (col - 576)] = val;
        } else {
            kvp_raw[i * 432 + (col - 720)] = val;
        }
    }
}

// ---------------- K2: rotate+translate; k_pts stored INTERLEAVED-PACKED ---------------
// kppack layout (f32x4 units): kppack4[(h*3+g)*NN + j] = kp[j][h*12+4g .. +3]
__global__ void k_pts_transform(const float* __restrict__ qp_raw, const float* __restrict__ kvp_raw,
                                const float* __restrict__ rot, const float* __restrict__ trans,
                                float* __restrict__ q_pts, float* __restrict__ kppack,
                                float* __restrict__ v_pts)
{
    int idx = blockIdx.x * blockDim.x + threadIdx.x;
    const int total = NN * HH * 16;
    if (idx >= total) return;
    int i = idx / (HH * 16);
    int r = idx % (HH * 16);
    int h = r / 16;
    int p = r % 16;

    float R[9], t3[3];
    for (int a = 0; a < 9; ++a) R[a] = rot[i * 9 + a];
    for (int a = 0; a < 3; ++a) t3[a] = trans[i * 3 + a];

    float x, y, zc;
    if (p < PQ) {
        x  = qp_raw[i * 144 + 0 * 48 + h * PQ + p];
        y  = qp_raw[i * 144 + 1 * 48 + h * PQ + p];
        zc = qp_raw[i * 144 + 2 * 48 + h * PQ + p];
    } else {
        int pp = p - PQ;
        x  = kvp_raw[i * 432 + 0 * 144 + h * 12 + pp];
        y  = kvp_raw[i * 432 + 1 * 144 + h * 12 + pp];
        zc = kvp_raw[i * 432 + 2 * 144 + h * 12 + pp];
    }
    float ox = R[0] * x + R[1] * y + R[2] * zc + t3[0];
    float oy = R[3] * x + R[4] * y + R[5] * zc + t3[1];
    float oz = R[6] * x + R[7] * y + R[8] * zc + t3[2];

    if (p < PQ) {
        int o = ((i * HH + h) * PQ + p) * 3;
        q_pts[o] = ox; q_pts[o + 1] = oy; q_pts[o + 2] = oz;
    } else {
        int pp = p - PQ;
        if (pp < PQ) {
            int d0 = pp * 3;
            kppack[(size_t)(((h * 3 + ((d0+0) >> 2)) * NN + i) * 4 + ((d0+0) & 3))] = ox;
            kppack[(size_t)(((h * 3 + ((d0+1) >> 2)) * NN + i) * 4 + ((d0+1) & 3))] = oy;
            kppack[(size_t)(((h * 3 + ((d0+2) >> 2)) * NN + i) * 4 + ((d0+2) & 3))] = oz;
        } else {
            int o = ((i * HH + h) * PV + (pp - PQ)) * 3;
            v_pts[o] = ox; v_pts[o + 1] = oy; v_pts[o + 2] = oz;
        }
    }
}

// ---------------- K_ATTN_PART: j-split; z staged to LDS (bf16, transposed+swizzled) ---
// VGPR cap raised to 128 (launch_bounds 512,4): per-wave MLP was the round-11 limiter
// (VGPR=32 -> 2-4 loads in flight). Phase A stores its bf16-converted z slice to
// zt[ch][row] (elem = ch*128 + (row ^ ((ch&15)<<3)), order-preserving 8-row runs);
// o_pair's 32 global scalar loads + cvts/thread become 4x bf16x8 LDS loads.
__global__ void __launch_bounds__(512, 4)
k_attn_part(const float* __restrict__ z, const float* __restrict__ Wb,
            const float* __restrict__ bb,
            const float* __restrict__ q, const float* __restrict__ kpack,
            const float* __restrict__ q_pts, const float* __restrict__ kppack,
            const float* __restrict__ head_weights, const float* __restrict__ mask,
            const float* __restrict__ v, const float* __restrict__ v_pts,
            float* __restrict__ stats, float* __restrict__ part,
            float* __restrict__ opair)
{
    __shared__ float lgs[HH][132];          // 6336 B
    __shared__ float q_lds[HH * CH];
    __shared__ float qp_lds[HH * PQ * 3];
    __shared__ float hw_lds[HH];
    __shared__ float bb_l[HH];
    __shared__ f32x4 pl[120][4];            // 7680 B (o/o_pt split-j partials)
    __shared__ __bf16 zt[128 * 128];        // 32768 B (z slice, [ch][row] swizzled)

    const int i  = blockIdx.x >> 2;
    const int jq = blockIdx.x & 3;
    const int j0 = jq * 128;
    const int tid = threadIdx.x;
    const int lane = tid & 63;
    const int wave = tid >> 6;
    const float* zbase = z + (size_t)i * NN * CZ;

    // ---- stage small per-i state ----
    if (tid < HH * CH)     q_lds[tid]  = q[(size_t)i * HH * CH + tid];
    if (tid < HH * PQ * 3) qp_lds[tid] = q_pts[(size_t)i * HH * PQ * 3 + tid];
    if (tid < HH) {
        float x = head_weights[tid];
        hw_lds[tid] = log1pf(expf(x)) * 0.13608276348795434f;  // softplus * sqrt(1/54)
        bb_l[tid] = bb[tid];
    }
    const float mask_i = mask[i];
    __syncthreads();

    // ---- Phase A: bias MFMA; wave w covers local j [16w,16w+16); z -> zt (bf16) ----
    {
        const float b_scale = 0.57735026918962576f;
        const int hcol = lane & 15;
        const int q8 = (lane >> 4) * 8;
        bf16x8 wbf[4];
        #pragma unroll
        for (int kc = 0; kc < 4; ++kc) {
            #pragma unroll
            for (int jj = 0; jj < 8; ++jj) {
                int c = kc * 32 + q8 + jj;
                float wv = (hcol < HH) ? Wb[c * HH + hcol] * b_scale : 0.0f;
                wbf[kc][jj] = (__bf16)wv;
            }
        }
        const int jl0 = wave * 16;
        const int row = jl0 + hcol;
        const float* zrow = zbase + (size_t)(j0 + row) * CZ;
        f32x4 acc = {0.f, 0.f, 0.f, 0.f};
        #pragma unroll
        for (int kc = 0; kc < 4; ++kc) {
            float4 z0 = *(const float4*)(zrow + kc * 32 + q8);
            float4 z1 = *(const float4*)(zrow + kc * 32 + q8 + 4);
            bf16x8 afrag;
            afrag[0] = (__bf16)z0.x; afrag[1] = (__bf16)z0.y;
            afrag[2] = (__bf16)z0.z; afrag[3] = (__bf16)z0.w;
            afrag[4] = (__bf16)z1.x; afrag[5] = (__bf16)z1.y;
            afrag[6] = (__bf16)z1.z; afrag[7] = (__bf16)z1.w;
            // stash bf16 z into transposed+swizzled LDS tile
            #pragma unroll
            for (int cc = 0; cc < 8; ++cc) {
                int ch = kc * 32 + q8 + cc;
                zt[ch * 128 + (row ^ ((ch & 15) << 3))] = afrag[cc];
            }
            acc = __builtin_amdgcn_mfma_f32_16x16x32_bf16(afrag, wbf[kc], acc, 0, 0, 0);
        }
        if (hcol < HH) {
            #pragma unroll
            for (int r = 0; r < 4; ++r)
                lgs[hcol][jl0 + (lane >> 4) * 4 + r] = acc[r];
        }
    }
    __syncthreads();

    // ---- Phase B: logits; 4 h-groups x 128 cols; packed float4, lane-coalesced ----
    {
        const float qk_scale = 0.14433756729740643f;  // sqrt(1/48)
        const float b_scale  = 0.57735026918962576f;  // sqrt(1/3)
        const int cl = tid & 127;
        const int j  = j0 + cl;
        const int hg = tid >> 7;           // 0..3 -> heads hg*3..hg*3+2 (wave-uniform)
        const float sqm = 100000.0f * (mask_i * mask[j] - 1.0f);
        const f32x4* kp4  = (const f32x4*)kpack;
        const f32x4* kpp4 = (const f32x4*)kppack;
        #pragma unroll
        for (int hh = 0; hh < 3; ++hh) {
            int h = hg * 3 + hh;
            const f32x4* kb = kp4 + (size_t)(h * 4) * NN + j;
            f32x4 k0 = kb[0 * NN];
            f32x4 k1 = kb[1 * NN];
            f32x4 k2 = kb[2 * NN];
            f32x4 k3 = kb[3 * NN];
            const float* ql = q_lds + h * CH;
            float accq = ql[0]*k0[0] + ql[1]*k0[1] + ql[2]*k0[2] + ql[3]*k0[3]
                       + ql[4]*k1[0] + ql[5]*k1[1] + ql[6]*k1[2] + ql[7]*k1[3]
                       + ql[8]*k2[0] + ql[9]*k2[1] + ql[10]*k2[2] + ql[11]*k2[3]
                       + ql[12]*k3[0] + ql[13]*k3[1] + ql[14]*k3[2] + ql[15]*k3[3];
            const f32x4* pb = kpp4 + (size_t)(h * 3) * NN + j;
            f32x4 pa = pb[0 * NN];
            f32x4 pm = pb[1 * NN];
            f32x4 pc = pb[2 * NN];
            const float* qh = qp_lds + h * 12;
            float t0 = qh[0]-pa[0],  t1 = qh[1]-pa[1],  t2 = qh[2]-pa[2],  t3 = qh[3]-pa[3];
            float t4 = qh[4]-pm[0],  t5 = qh[5]-pm[1],  t6 = qh[6]-pm[2],  t7 = qh[7]-pm[3];
            float t8 = qh[8]-pc[0],  t9 = qh[9]-pc[1],  t10= qh[10]-pc[2], t11= qh[11]-pc[3];
            float s2 = t0*t0 + t1*t1 + t2*t2 + t3*t3
                     + t4*t4 + t5*t5 + t6*t6 + t7*t7
                     + t8*t8 + t9*t9 + t10*t10 + t11*t11;
            lgs[h][cl] += accq * qk_scale + b_scale * bb_l[h] - 0.5f * hw_lds[h] * s2 + sqm;
        }
    }
    __syncthreads();

    // ---- partial softmax: wave w handles rows w, w+8; 2 vals/lane ----
    for (int row = wave; row < HH; row += 8) {
        float v0 = lgs[row][lane];
        float v1 = lgs[row][lane + 64];
        float m = fmaxf(v0, v1);
        #pragma unroll
        for (int off = 32; off >= 1; off >>= 1) m = fmaxf(m, __shfl_xor(m, off));
        float e0 = expf(v0 - m);
        float e1 = expf(v1 - m);
        float ss = e0 + e1;
        #pragma unroll
        for (int off = 32; off >= 1; off >>= 1) ss += __shfl_xor(ss, off);
        lgs[row][lane]      = e0;
        lgs[row][lane + 64] = e1;
        if (lane == 0) {
            size_t sb = ((size_t)(i * 4 + jq) * HH + row) * 2;
            stats[sb]     = m;
            stats[sb + 1] = ss;
        }
    }
    __syncthreads();

    // ---- o / o_pt partials: thread = (jsub, f4); explicit 8-deep load batching ----
    if (tid < 480) {
        int jsub = tid / 120;         // 0..3 (slow index: lanes share jsub)
        int f4   = tid % 120;         // 0..119 float4-output (fast across lanes)
        int h = (f4 < 48) ? (f4 >> 2) : ((f4 - 48) / 6);
        const float* lrj = lgs[h] + jsub * 32;
        const float* bp;
        int stride;
        if (f4 < 48) { bp = v     + (size_t)j0 * 192 + f4 * 4;        stride = 192; }
        else         { bp = v_pts + (size_t)j0 * 288 + (f4 - 48) * 4; stride = 288; }
        bp += (size_t)(jsub * 32) * stride;
        f32x4 acc = {0.f, 0.f, 0.f, 0.f};
        #pragma unroll
        for (int c = 0; c < 4; ++c) {
            f32x4 t[8];
            #pragma unroll
            for (int u = 0; u < 8; ++u)
                t[u] = *(const f32x4*)(bp + (size_t)(c * 8 + u) * stride);
            #pragma unroll
            for (int u = 0; u < 8; ++u)
                acc += lrj[c * 8 + u] * t[u];
        }
        pl[f4][jsub] = acc;
    }

    // ---- o_pair partial MFMA: p (LDS) x z (zt LDS, bf16x8 direct B-frag); 4 K-steps --
    {
        int cl = lane & 15;
        int q4 = lane >> 4;
        int ha = (cl < HH) ? cl : (HH - 1);
        int cb = wave * 16 + cl;              // 0..127 = z channel
        const int X = (cb & 15) << 3;
        f32x4 pacc = {0.f, 0.f, 0.f, 0.f};
        #pragma unroll
        for (int ks = 0; ks < 4; ++ks) {
            int jb = ks * 32 + q4 * 8;        // local j (multiple of 8)
            f32x4 a0 = *(const f32x4*)&lgs[ha][jb];
            f32x4 a1 = *(const f32x4*)&lgs[ha][jb + 4];
            bf16x8 af;
            af[0] = (__bf16)a0[0]; af[1] = (__bf16)a0[1];
            af[2] = (__bf16)a0[2]; af[3] = (__bf16)a0[3];
            af[4] = (__bf16)a1[0]; af[5] = (__bf16)a1[1];
            af[6] = (__bf16)a1[2]; af[7] = (__bf16)a1[3];
            bf16x8 bfv = *(const bf16x8*)&zt[cb * 128 + (jb ^ X)];
            pacc = __builtin_amdgcn_mfma_f32_16x16x32_bf16(af, bfv, pacc, 0, 0, 0);
        }
        #pragma unroll
        for (int r = 0; r < 4; ++r) {
            int h = q4 * 4 + r;
            if (h < HH)
                opair[(size_t)(i * 4 + jq) * 1536 + h * 128 + cb] = pacc[r];
        }
    }
    __syncthreads();

    // ---- combine split-j partials; float4 write ----
    if (tid < 120) {
        f32x4 s = pl[tid][0] + pl[tid][1] + pl[tid][2] + pl[tid][3];
        *(f32x4*)&part[(size_t)(i * 4 + jq) * 480 + tid * 4] = s;
    }
}

// ---------------- K_COMBINE: merge 4 j-quarters (flash combine) + frame + norms ------
__global__ void __launch_bounds__(512, 8)
k_combine(const float* __restrict__ stats, const float* __restrict__ part,
          const float* __restrict__ opair,
          const float* __restrict__ rot, const float* __restrict__ trans,
          float* __restrict__ cat)
{
    __shared__ float f_lds[HH][4];
    __shared__ float opt_lds[HH * PV * 3];

    const int i = blockIdx.x;
    const int tid = threadIdx.x;

    if (tid < HH) {
        float m[4], s[4];
        #pragma unroll
        for (int qq = 0; qq < 4; ++qq) {
            size_t sb = ((size_t)(i * 4 + qq) * HH + tid) * 2;
            m[qq] = stats[sb];
            s[qq] = stats[sb + 1];
        }
        float M = fmaxf(fmaxf(m[0], m[1]), fmaxf(m[2], m[3]));
        float Z = 0.f;
        float e[4];
        #pragma unroll
        for (int qq = 0; qq < 4; ++qq) { e[qq] = expf(m[qq] - M); Z += s[qq] * e[qq]; }
        float invZ = 1.0f / Z;
        #pragma unroll
        for (int qq = 0; qq < 4; ++qq) f_lds[tid][qq] = e[qq] * invZ;
    }
    __syncthreads();

    // ---- o and o_pt ----
    if (tid < 480) {
        int h = (tid < 192) ? (tid >> 4) : ((tid - 192) / 24);
        float acc = 0.f;
        #pragma unroll
        for (int qq = 0; qq < 4; ++qq)
            acc += f_lds[h][qq] * part[(size_t)(i * 4 + qq) * 480 + tid];
        if (tid < 192) cat[(size_t)i * 2112 + tid] = acc;
        else           opt_lds[tid - 192] = acc;
    }

    // ---- o_pair: 1536 outputs, 3 per thread ----
    #pragma unroll
    for (int k = 0; k < 3; ++k) {
        int idx = tid + k * 512;
        int h = idx >> 7;
        float acc = 0.f;
        #pragma unroll
        for (int qq = 0; qq < 4; ++qq)
            acc += f_lds[h][qq] * opair[(size_t)(i * 4 + qq) * 1536 + idx];
        cat[(size_t)i * 2112 + 576 + idx] = acc;
    }
    __syncthreads();

    // ---- inverse frame + norm ----
    if (tid < HH * PV) {
        int hp = tid;
        float R[9], t3[3];
        #pragma unroll
        for (int a2 = 0; a2 < 9; ++a2) R[a2] = rot[i * 9 + a2];
        #pragma unroll
        for (int a2 = 0; a2 < 3; ++a2) t3[a2] = trans[i * 3 + a2];
        float gx = opt_lds[hp * 3 + 0] - t3[0];
        float gy = opt_lds[hp * 3 + 1] - t3[1];
        float gz = opt_lds[hp * 3 + 2] - t3[2];
        float lx = R[0] * gx + R[3] * gy + R[6] * gz;
        float ly = R[1] * gx + R[4] * gy + R[7] * gz;
        float lz = R[2] * gx + R[5] * gy + R[8] * gz;
        float* crow = cat + (size_t)i * 2112;
        crow[192 + 0 * 96 + hp] = lx;
        crow[192 + 1 * 96 + hp] = ly;
        crow[192 + 2 * 96 + hp] = lz;
        crow[480 + hp] = sqrtf(lx * lx + ly * ly + lz * lz + 1e-8f);
    }
}

// ---------------- K7: out = cat @ Wout + bout — BM=16 split-K GEMM ----------------
__global__ void k_final(const float* __restrict__ cat, const float* __restrict__ Wout,
                        const float* __restrict__ bout, float* __restrict__ out)
{
    __shared__ float As[16 * 52];
    __shared__ float Bs[48 * 64];

    int tx = threadIdx.x & 15;
    int ty = threadIdx.x >> 4;
    int n0 = blockIdx.x * 64;
    int m0 = blockIdx.y * 16;
    int k0 = blockIdx.z * 528;

    float acc[4] = {0.f, 0.f, 0.f, 0.f};

    for (int stage = 0; stage < 11; ++stage) {
        int kb = k0 + stage * 48;
        #pragma unroll
        for (int e = 0; e < 3; ++e) {
            int idx = e * 256 + threadIdx.x;
            int m = idx / 48, kk = idx % 48;
            As[m * 52 + kk] = cat[(size_t)(m0 + m) * 2112 + kb + kk];
        }
        #pragma unroll
        for (int e = 0; e < 12; ++e) {
            int idx = e * 256 + threadIdx.x;
            int kk = idx >> 6, n = idx & 63;
            Bs[kk * 64 + n] = Wout[(size_t)(kb + kk) * 384 + n0 + n];
        }
        __syncthreads();

        for (int kk = 0; kk < 48; kk += 4) {
            f32x4 a = *(const f32x4*)&As[ty * 52 + kk];
            f32x4 b[4];
            #pragma unroll
            for (int kq = 0; kq < 4; ++kq)
                b[kq] = *(const f32x4*)&Bs[(kk + kq) * 64 + tx * 4];
            #pragma unroll
            for (int kq = 0; kq < 4; ++kq)
                #pragma unroll
                for (int cc = 0; cc < 4; ++cc)
                    acc[cc] += a[kq] * b[kq][cc];
        }
        __syncthreads();
    }

    bool add_bias = (blockIdx.z == 0);
    int m = m0 + ty;
    #pragma unroll
    for (int cc = 0; cc < 4; ++cc) {
        int n = n0 + tx * 4 + cc;
        float val = acc[cc] + (add_bias ? bout[n] : 0.f);
        atomicAdd(&out[(size_t)m * 384 + n], val);
    }
}

extern "C" void kernel_launch(void* const* d_in, const int* in_sizes, int n_in,
                              void* d_out, int out_size, void* d_ws, size_t ws_size,
                              hipStream_t stream)
{
    const float* s     = (const float*)d_in[0];
    const float* z     = (const float*)d_in[1];
    const float* rot   = (const float*)d_in[2];
    const float* trans = (const float*)d_in[3];
    const float* mask  = (const float*)d_in[4];
    const float* Wq    = (const float*)d_in[5];
    const float* bq    = (const float*)d_in[6];
    const float* Wkv   = (const float*)d_in[7];
    const float* bkv   = (const float*)d_in[8];
    const float* Wqp   = (const float*)d_in[9];
    const float* bqp   = (const float*)d_in[10];
    const float* Wkvp  = (const float*)d_in[11];
    const float* bkvp  = (const float*)d_in[12];
    const float* Wb    = (const float*)d_in[13];
    const float* bb    = (const float*)d_in[14];
    const float* hw    = (const float*)d_in[15];
    const float* Wout  = (const float*)d_in[16];
    const float* bout  = (const float*)d_in[17];
    float* out = (float*)d_out;

    float* ws = (float*)d_ws;
    float* q       = ws;             // 98304
    float* kpack   = ws + 98304;     // 98304 (interleaved [h][4][j][4])
    float* v       = ws + 196608;    // 98304 (natural [j][192])
    float* qp_raw  = ws + 294912;    // 73728
    float* kvp_raw = ws + 368640;    // 221184
    float* q_pts   = ws + 589824;    // 73728
    float* kppack  = ws + 663552;    // 73728 (interleaved [h][3][j][4])
    float* v_pts   = ws + 737280;    // 147456 (natural [j][288])
    float* cat     = ws + 884736;    // 1081344
    float* Wcat    = ws + 1966080;   // 442368
    float* bcat    = ws + 2408448;   // 1152
    float* stats   = ws + 2409600;   // 49152
    float* part    = ws + 2458752;   // 983040
    float* opairb  = ws + 3441792;   // 3145728

    hipMemsetAsync(out, 0, (size_t)NN * CS * sizeof(float), stream);

    hipLaunchKernelGGL(k_repack, dim3(512), dim3(256), 0, stream,
                       Wq, bq, Wkv, bkv, Wqp, bqp, Wkvp, bkvp, Wcat, bcat);
    hipLaunchKernelGGL(k_proj, dim3(18, 32), dim3(256), 0, stream,
                       s, Wcat, bcat, q, kpack, v, qp_raw, kvp_raw);
    hipLaunchKernelGGL(k_pts_transform, dim3(384), dim3(256), 0, stream,
                       qp_raw, kvp_raw, rot, trans, q_pts, kppack, v_pts);
    hipLaunchKernelGGL(k_attn_part, dim3(NN * 4), dim3(512), 0, stream,
                       z, Wb, bb, q, kpack, q_pts, kppack, hw, mask,
                       v, v_pts, stats, part, opairb);
    hipLaunchKernelGGL(k_combine, dim3(NN), dim3(512), 0, stream,
                       stats, part, opairb, rot, trans, cat);
    hipLaunchKernelGGL(k_final, dim3(6, 32, 4), dim3(256), 0, stream, cat, Wout, bout, out);
}